// Round 1
// baseline (244.705 us; speedup 1.0000x reference)
//
#include <hip/hip_runtime.h>
#include <hip/hip_bf16.h>

// Gated delta-rule recurrent cell, single step.
// B=128, H=16, Dk=Dv=128. One block per (b,h); 256 threads.
// Each thread owns a 16(k) x 4(v) float4-tiled register sub-tile of the
// 128x128 state. Single pass: load state once, accumulate A[v]=S^T k and
// Bq[v]=S^T q partials on the fly, LDS-reduce, compute delta, rewrite state.
// out[v] = decay*Bq[v] + (k.q)*delta[v]   (algebraic identity, avoids 2nd pass)

#define DK 128
#define DV 128

__global__ __launch_bounds__(256) void s1_cell_kernel(
    const float* __restrict__ q,
    const float* __restrict__ k,
    const float* __restrict__ v,
    const float* __restrict__ g,
    const float* __restrict__ beta,
    const float* __restrict__ S,
    float* __restrict__ out,      // full d_out
    int BH)
{
    const int bh = blockIdx.x;
    const size_t stile = (size_t)bh * DK * DV;
    const float* __restrict__ Sb   = S + stile;
    float* __restrict__ out_o      = out + (size_t)bh * DV;
    float* __restrict__ out_S      = out + (size_t)BH * DV + stile;

    __shared__ float kt[DK];
    __shared__ float qt[DK];
    __shared__ float vt[DV];
    __shared__ float apart[8][DV];   // partial sums of S^T k, per k-group
    __shared__ float bpart[8][DV];   // partial sums of S^T q
    __shared__ float sdelta[DV];
    __shared__ float s_kq;

    const int t = threadIdx.x;

    if (t < DK) {
        kt[t] = k[bh * DK + t];
        qt[t] = q[bh * DK + t];
        vt[t] = v[bh * DV + t];
    }
    __syncthreads();

    const float decay = expf(g[bh]);
    const float bta   = beta[bh];

    // --- k.q reduction (wave 0) ---
    if (t < 64) {
        float val = kt[t] * qt[t] + kt[t + 64] * qt[t + 64];
        #pragma unroll
        for (int off = 32; off > 0; off >>= 1)
            val += __shfl_down(val, off, 64);
        if (t == 0) s_kq = val;
    }

    // --- main pass: load 16x4 tile, accumulate A/Bq partials ---
    const int vb = (t & 31) * 4;     // v base: 0..124
    const int kb = (t >> 5) * 16;    // k base: 0..112 (8 groups)

    float4 s[16];
    float a0 = 0.f, a1 = 0.f, a2 = 0.f, a3 = 0.f;
    float b0 = 0.f, b1 = 0.f, b2 = 0.f, b3 = 0.f;

    #pragma unroll
    for (int i = 0; i < 16; ++i) {
        const int kk = kb + i;
        s[i] = *(const float4*)(Sb + (size_t)kk * DV + vb);
        const float kv = kt[kk];
        const float qv = qt[kk];
        a0 += s[i].x * kv;  a1 += s[i].y * kv;  a2 += s[i].z * kv;  a3 += s[i].w * kv;
        b0 += s[i].x * qv;  b1 += s[i].y * qv;  b2 += s[i].z * qv;  b3 += s[i].w * qv;
    }
    const int grp = t >> 5;
    apart[grp][vb + 0] = a0;  apart[grp][vb + 1] = a1;
    apart[grp][vb + 2] = a2;  apart[grp][vb + 3] = a3;
    bpart[grp][vb + 0] = b0;  bpart[grp][vb + 1] = b1;
    bpart[grp][vb + 2] = b2;  bpart[grp][vb + 3] = b3;
    __syncthreads();

    // --- finish reductions, compute delta and out (128 threads) ---
    if (t < DV) {
        float A = 0.f, Bq = 0.f;
        #pragma unroll
        for (int j = 0; j < 8; ++j) {
            A  += apart[j][t];
            Bq += bpart[j][t];
        }
        const float dlt = (vt[t] - decay * A) * bta;
        sdelta[t] = dlt;
        out_o[t] = decay * Bq + s_kq * dlt;
    }
    __syncthreads();

    // --- rewrite state: S' = decay*S + k[k]*delta[v] ---
    const float d0 = sdelta[vb + 0];
    const float d1 = sdelta[vb + 1];
    const float d2 = sdelta[vb + 2];
    const float d3 = sdelta[vb + 3];

    #pragma unroll
    for (int i = 0; i < 16; ++i) {
        const int kk = kb + i;
        const float ktk = kt[kk];
        float4 r;
        r.x = decay * s[i].x + ktk * d0;
        r.y = decay * s[i].y + ktk * d1;
        r.z = decay * s[i].z + ktk * d2;
        r.w = decay * s[i].w + ktk * d3;
        *(float4*)(out_S + (size_t)kk * DV + vb) = r;
    }
}

extern "C" void kernel_launch(void* const* d_in, const int* in_sizes, int n_in,
                              void* d_out, int out_size, void* d_ws, size_t ws_size,
                              hipStream_t stream) {
    const float* q    = (const float*)d_in[0];
    const float* k    = (const float*)d_in[1];
    const float* v    = (const float*)d_in[2];
    const float* g    = (const float*)d_in[3];
    const float* beta = (const float*)d_in[4];
    const float* S    = (const float*)d_in[5];
    float* out = (float*)d_out;

    const int BH = in_sizes[3];   // g has B*H elements = 2048

    s1_cell_kernel<<<BH, 256, 0, stream>>>(q, k, v, g, beta, S, out, BH);
}